// Round 5
// baseline (502.943 us; speedup 1.0000x reference)
//
#include <hip/hip_runtime.h>
#include <math.h>

#define B 2
#define N 8192
#define M 8192
#define D 64
#define KNN 16
#define BM (B * M)           // 16384
#define GC 16                // grid cells per axis
#define NC (GC * GC * GC)    // 4096
#define NSC 64               // supercells (4x4x4)
#define WTMAX 192            // max wave-table entries per batch
#define CAP 48               // per-lane LDS candidate buffer slots
#define CAPT 1536            // LDS point-tile capacity

// Sorted-insert of (dd,ii) into per-lane top-16 (v ascending). Strict < keeps
// earlier-inserted on exact ties.
#define CHAIN_INSERT(DVAL, IVAL) do {                                   \
    float _dd = (DVAL); int _ii = (IVAL);                               \
    _Pragma("unroll")                                                   \
    for (int _r = 0; _r < KNN; ++_r) {                                  \
        bool  _sm = _dd < v[_r];                                        \
        float _tv = v[_r]; int _ti = id[_r];                            \
        v[_r]  = _sm ? _dd : _tv;  id[_r] = _sm ? _ii : _ti;            \
        _dd    = _sm ? _tv : _dd;  _ii    = _sm ? _ti : _ii;            \
    }                                                                   \
} while (0)

// Drain per-lane buffered candidates (tile positions) into the top-16 lists.
#define DRAIN() do {                                                    \
    int _mx = cnt;                                                      \
    _Pragma("unroll")                                                   \
    for (int _o = 32; _o; _o >>= 1)                                     \
        _mx = max(_mx, __shfl_xor(_mx, _o, 64));                        \
    _mx = __builtin_amdgcn_readfirstlane(_mx);                          \
    for (int _dt = 0; _dt < _mx; ++_dt) {                               \
        float _dv = fbuf[_dt][lane];                                    \
        int _jj = (int)tidx[ibuf[_dt][lane]];                           \
        if (_dt < cnt && _dv < v[KNN - 1]) CHAIN_INSERT(_dv, _jj);      \
    }                                                                   \
    cnt = 0; thr = v[KNN - 1];                                          \
} while (0)

// Scan tile[0..cur), filter vs thr into the buffer, then drain; reset tile.
#define FLUSH() do {                                                    \
    int _end = cur;                                                     \
    for (int _t = 0; _t < _end; ++_t) {                                 \
        float4 _p = tile[_t];                      /* broadcast b128 */ \
        float _dv = fmaf(ax, _p.x, _p.w);                               \
        _dv = fmaf(ay, _p.y, _dv);                                      \
        _dv = fmaf(az, _p.z, _dv);                                      \
        if (warm < 16) {                           /* wave-uniform   */ \
            int _jw = (int)tidx[_t];                                    \
            CHAIN_INSERT(_dv, _jw);                                     \
            if (++warm == 16) thr = v[KNN - 1];                         \
        } else if (_dv < thr) {                                         \
            if (cnt < CAP) {                                            \
                fbuf[cnt][lane] = _dv;                                  \
                ibuf[cnt][lane] = (unsigned short)_t;                   \
                ++cnt;                                                  \
            } else {                               /* overflow: rare */ \
                int _jo = (int)tidx[_t];                                \
                CHAIN_INSERT(_dv, _jo);                                 \
                thr = v[KNN - 1];                                       \
            }                                                           \
        }                                                               \
    }                                                                   \
    DRAIN();                                                            \
    cur = 0;                                                            \
} while (0)

// Cooperatively stage sorted-point range [ST,EN) into the tile (vector loads).
#define STAGE(ST, EN) do {                                              \
    int _st = (ST), _len = (EN) - (ST), _off = 0;                       \
    while (_off < _len) {                                               \
        if (cur == CAPT) FLUSH();                                       \
        int _take = min(_len - _off, CAPT - cur);                       \
        for (int _u = lane; _u < _take; _u += 64) {                     \
            tile[cur + _u] = spts[pb + _st + _off + _u];                \
            tidx[cur + _u] = (unsigned short)(_st + _off + _u);         \
        }                                                               \
        cur += _take; _off += _take;                                    \
    }                                                                   \
} while (0)

// ---------------------------------------------------------------------------
// Kernel: histogram points into 4096 linear cells, queries into 64 supercells.
__global__ __launch_bounds__(256) void k_count(const float* __restrict__ xyz1,
                                               const float* __restrict__ xyz2,
                                               unsigned* __restrict__ pcount,
                                               unsigned* __restrict__ qcount) {
    int i = blockIdx.x * 256 + threadIdx.x;   // < B*N
    int b = i >> 13;
    const float* p = xyz1 + (size_t)i * 3;
    int cx = max(0, min(GC - 1, (int)(p[0] * GC)));
    int cy = max(0, min(GC - 1, (int)(p[1] * GC)));
    int cz = max(0, min(GC - 1, (int)(p[2] * GC)));
    atomicAdd(&pcount[b * NC + (cz * GC + cy) * GC + cx], 1u);
    const float* q = xyz2 + (size_t)i * 3;
    int qx = max(0, min(GC - 1, (int)(q[0] * GC)));
    int qy = max(0, min(GC - 1, (int)(q[1] * GC)));
    int qz = max(0, min(GC - 1, (int)(q[2] * GC)));
    int sc = ((qz >> 2) * 4 + (qy >> 2)) * 4 + (qx >> 2);
    atomicAdd(&qcount[b * NSC + sc], 1u);
}

// Kernel: blocks 0,1 = 4096-bin exclusive scan (points, per batch);
//         blocks 2,3 = 64-bin query scan + wave-table build (serial, tiny).
__global__ __launch_bounds__(256) void k_scan(const unsigned* __restrict__ pcount,
                                              const unsigned* __restrict__ qcount,
                                              unsigned* __restrict__ pstart,
                                              unsigned* __restrict__ pcur,
                                              unsigned* __restrict__ qcur,
                                              int* __restrict__ wtab,
                                              int* __restrict__ ntab) {
    __shared__ unsigned wsum[4];
    int blk = blockIdx.x;
    if (blk < 2) {
        int b = blk;
        int t = threadIdx.x;
        int base = b * NC + t * 16;
        unsigned c[16]; unsigned tsum = 0;
#pragma unroll
        for (int k = 0; k < 16; ++k) { c[k] = pcount[base + k]; tsum += c[k]; }
        int lane = t & 63, wv = t >> 6;
        unsigned x = tsum;
#pragma unroll
        for (int off = 1; off < 64; off <<= 1) {
            unsigned y = __shfl_up(x, off, 64);
            if (lane >= off) x += y;
        }
        if (lane == 63) wsum[wv] = x;
        __syncthreads();
        unsigned pre = 0;
        for (int k2 = 0; k2 < wv; ++k2) pre += wsum[k2];
        unsigned run = pre + x - tsum;
#pragma unroll
        for (int k = 0; k < 16; ++k) {
            pstart[base + k] = run; pcur[base + k] = run; run += c[k];
        }
    } else {
        int b = blk - 2;
        if (threadIdx.x != 0) return;
        int run = 0, nw = 0;
        for (int sc = 0; sc < NSC; ++sc) {
            int c = (int)qcount[b * NSC + sc];
            qcur[b * NSC + sc] = (unsigned)run;
            for (int o = 0; o < c; o += 64) {
                int num = min(64, c - o);
                wtab[b * WTMAX + nw++] = ((run + o) << 7) | num;
            }
            run += c;
        }
        ntab[b] = nw;
    }
}

// Kernel: scatter points (cell-sorted, with |p|^2) and queries (supercell-sorted).
__global__ __launch_bounds__(256) void k_scatter(const float* __restrict__ xyz1,
                                                 const float* __restrict__ xyz2,
                                                 unsigned* __restrict__ pcur,
                                                 unsigned* __restrict__ qcur,
                                                 float4* __restrict__ spts,
                                                 int* __restrict__ sidx,
                                                 float4* __restrict__ squery) {
    int i = blockIdx.x * 256 + threadIdx.x;   // < B*N
    int b = i >> 13;
    const float* p = xyz1 + (size_t)i * 3;
    float x = p[0], y = p[1], z = p[2];
    int cx = max(0, min(GC - 1, (int)(x * GC)));
    int cy = max(0, min(GC - 1, (int)(y * GC)));
    int cz = max(0, min(GC - 1, (int)(z * GC)));
    unsigned pos = atomicAdd(&pcur[b * NC + (cz * GC + cy) * GC + cx], 1u);
    spts[(size_t)b * N + pos] = make_float4(x, y, z, fmaf(x, x, fmaf(y, y, z * z)));
    sidx[(size_t)b * N + pos] = i & (N - 1);

    const float* q = xyz2 + (size_t)i * 3;
    float qx = q[0], qy = q[1], qz = q[2];
    int ax = max(0, min(GC - 1, (int)(qx * GC)));
    int ay = max(0, min(GC - 1, (int)(qy * GC)));
    int az = max(0, min(GC - 1, (int)(qz * GC)));
    int sc = ((az >> 2) * 4 + (ay >> 2)) * 4 + (ax >> 2);
    unsigned qpos = atomicAdd(&qcur[b * NSC + sc], 1u);
    squery[(size_t)b * M + qpos] = make_float4(qx, qy, qz, __int_as_float(i));
}

// Kernel: f = feature1 @ Wp + bp. Wave per row, lane = output channel.
__global__ __launch_bounds__(256) void k_proj(const float* __restrict__ feat,
                                              const float* __restrict__ Wp,
                                              const float* __restrict__ bp,
                                              float* __restrict__ f) {
    int c   = threadIdx.x & 63;
    int row = blockIdx.x * 4 + (threadIdx.x >> 6);   // 0..B*N-1
    const float* fr = feat + (size_t)row * 64;       // wave-uniform -> s_load
    float acc = bp[c];
#pragma unroll 8
    for (int d = 0; d < 64; ++d)
        acc = fmaf(fr[d], Wp[d * 64 + c], acc);
    f[(size_t)row * 64 + c] = acc;
}

// Kernel: exact grid KNN. One wave per <=64-query supercell group.
// Expanding-box shells; each shell's rows are STAGED into LDS with
// cooperative 64-lane vector loads, then scanned via broadcast ds_read_b128
// (per-lane threshold filter -> buffer -> per-radius chain drains).
// Per-lane exact stop bound vs box complement.
__global__ __launch_bounds__(64) void k_knn(const float4* __restrict__ spts,
                                            const int* __restrict__ sidx,
                                            const float4* __restrict__ squery,
                                            const unsigned* __restrict__ pstart,
                                            const unsigned* __restrict__ pcount,
                                            const int* __restrict__ wtab,
                                            const int* __restrict__ ntab,
                                            int* __restrict__ idx_out,
                                            float* __restrict__ w_out) {
    __shared__ float4 tile[CAPT];              // 24 KB
    __shared__ unsigned short tidx[CAPT];      //  3 KB
    __shared__ float          fbuf[CAP][64];   // 12 KB
    __shared__ unsigned short ibuf[CAP][64];   //  6 KB
    int blk = blockIdx.x;
    int b = blk >= WTMAX ? 1 : 0;
    int ti = blk - b * WTMAX;
    if (ti >= ntab[b]) return;
    int e = wtab[b * WTMAX + ti];
    int qoff = e >> 7, qnum = e & 127;
    int lane = threadIdx.x;
    int sl = lane < qnum ? lane : qnum - 1;    // surplus lanes: dup last query
    float4 sq = squery[(size_t)b * M + qoff + sl];
    int gq = lane < qnum ? __float_as_int(sq.w) : -1;
    float qx = sq.x, qy = sq.y, qz = sq.z;
    float ax = -2.f * qx, ay = -2.f * qy, az = -2.f * qz;
    float q2 = fmaf(qx, qx, fmaf(qy, qy, qz * qz));

    int cx = max(0, min(GC - 1, (int)(qx * GC)));
    int cy = max(0, min(GC - 1, (int)(qy * GC)));
    int cz = max(0, min(GC - 1, (int)(qz * GC)));
    int mnx = cx, mxx = cx, mny = cy, mxy = cy, mnz = cz, mxz = cz;
#pragma unroll
    for (int off = 1; off < 64; off <<= 1) {
        mnx = min(mnx, __shfl_xor(mnx, off, 64));
        mxx = max(mxx, __shfl_xor(mxx, off, 64));
        mny = min(mny, __shfl_xor(mny, off, 64));
        mxy = max(mxy, __shfl_xor(mxy, off, 64));
        mnz = min(mnz, __shfl_xor(mnz, off, 64));
        mxz = max(mxz, __shfl_xor(mxz, off, 64));
    }
    mnx = __builtin_amdgcn_readfirstlane(mnx);
    mxx = __builtin_amdgcn_readfirstlane(mxx);
    mny = __builtin_amdgcn_readfirstlane(mny);
    mxy = __builtin_amdgcn_readfirstlane(mxy);
    mnz = __builtin_amdgcn_readfirstlane(mnz);
    mxz = __builtin_amdgcn_readfirstlane(mxz);

    float v[KNN]; int id[KNN];
#pragma unroll
    for (int r = 0; r < KNN; ++r) { v[r] = 3.4e38f; id[r] = 0; }
    float thr = 3.4e38f;
    int warm = 0, cnt = 0, cur = 0;
    int pb = b * N, cb = b * NC;
    int x0p = 0, x1p = -1, y0p = 0, y1p = -1, z0p = 0, z1p = -1;

    for (int r = 0; r < GC; ++r) {
        int x0 = max(mnx - r, 0), x1 = min(mxx + r, GC - 1);
        int y0 = max(mny - r, 0), y1 = min(mxy + r, GC - 1);
        int z0 = max(mnz - r, 0), z1 = min(mxz + r, GC - 1);
        for (int zz = z0; zz <= z1; ++zz)
        for (int yy = y0; yy <= y1; ++yy) {
            int a0 = x0, a1 = x1, c0 = 1, c1 = 0;           // run C empty
            if (zz >= z0p && zz <= z1p && yy >= y0p && yy <= y1p) {
                a1 = x0p - 1; c0 = x1p + 1; c1 = x1;        // exclude interior
            }
            for (int pass2 = 0; pass2 < 2; ++pass2) {
                int lo = pass2 ? c0 : a0, hi = pass2 ? c1 : a1;
                if (lo > hi) continue;
                int codeL = cb + (zz * GC + yy) * GC + lo;  // x-contiguous run
                int st = (int)pstart[codeL];
                int en = (int)pstart[codeL + (hi - lo)] + (int)pcount[codeL + (hi - lo)];
                st = __builtin_amdgcn_readfirstlane(st);
                en = __builtin_amdgcn_readfirstlane(en);
                STAGE(st, en);
            }
        }
        FLUSH();                                            // scan + drain
        // per-lane lower bound on d^2 of any point outside box(r)
        float lox = x0 * (1.f / GC), hix = (x1 + 1) * (1.f / GC);
        float loy = y0 * (1.f / GC), hiy = (y1 + 1) * (1.f / GC);
        float loz = z0 * (1.f / GC), hiz = (z1 + 1) * (1.f / GC);
        float bx = fminf(x0 > 0 ? qx - lox : 1e30f, x1 < GC - 1 ? hix - qx : 1e30f);
        float by = fminf(y0 > 0 ? qy - loy : 1e30f, y1 < GC - 1 ? hiy - qy : 1e30f);
        float bz = fminf(z0 > 0 ? qz - loz : 1e30f, z1 < GC - 1 ? hiz - qz : 1e30f);
        float lb = fminf(bx, fminf(by, bz));
        if (__all(v[KNN - 1] + q2 <= lb * lb * 0.99999f)) break;
        x0p = x0; x1p = x1; y0p = y0; y1p = y1; z0p = z0; z1p = z1;
    }

    if (gq >= 0) {
        w_out[gq] = (v[0] + q2 > 0.03f) ? 10.0f : 1.0f;
#pragma unroll
        for (int r2 = 0; r2 < KNN; ++r2)
            idx_out[(size_t)r2 * BM + gq] = sidx[pb + id[r2]];
    }
}

// Kernel: gather + MLP + reduce. One wave per query, lane = channel c.
__global__ __launch_bounds__(256) void k_final(const float* __restrict__ xyz1,
                                               const float* __restrict__ xyz2,
                                               const float* __restrict__ f,
                                               const int* __restrict__ idx,
                                               const float* __restrict__ W1,
                                               const float* __restrict__ b1,
                                               const float* __restrict__ W2,
                                               const float* __restrict__ b2,
                                               float* __restrict__ out) {
    __shared__ float w2s[64 * 64];      // 16 KB, [d][c]
    __shared__ float hT[4][64 * 16];    // 16 KB, per-wave [d][k]

    for (int t = threadIdx.x; t < 64 * 16; t += 256)
        ((float4*)w2s)[t] = ((const float4*)W2)[t];

    int wv = threadIdx.x >> 6;
    int c  = threadIdx.x & 63;
    int gq = blockIdx.x * 4 + wv;
    int b  = gq >> 13;

    const float* q = xyz2 + (size_t)gq * 3;
    float qx = q[0], qy = q[1], qz = q[2];
    float w10 = W1[c], w11 = W1[64 + c], w12 = W1[128 + c];
    float b1c = b1[c], b2c = b2[c];

    int nidx[KNN];
#pragma unroll
    for (int k = 0; k < KNN; ++k)
        nidx[k] = idx[(size_t)k * BM + gq];      // wave-broadcast load

    float h[KNN];
#pragma unroll
    for (int k = 0; k < KNN; ++k) {
        const float* p = xyz1 + ((size_t)b * N + nidx[k]) * 3;
        float gx = p[0] - qx, gy = p[1] - qy, gz = p[2] - qz;
        float t = fmaf(gx, w10, b1c);
        t = fmaf(gy, w11, t);
        t = fmaf(gz, w12, t);
        h[k] = fmaxf(t, 0.f);
    }

#pragma unroll
    for (int k = 0; k < KNN; k += 4)
        *(float4*)&hT[wv][c * 16 + k] = make_float4(h[k], h[k+1], h[k+2], h[k+3]);

    __syncthreads();   // covers W2 staging + hT visibility

    float y[KNN];
#pragma unroll
    for (int k = 0; k < KNN; ++k) y[k] = 0.f;

#pragma unroll 4
    for (int d = 0; d < 64; ++d) {
        float w2dc = w2s[d * 64 + c];                       // conflict-free
        const float4* hp = (const float4*)&hT[wv][d * 16];  // broadcast reads
        float hh[16];
        *(float4*)&hh[0]  = hp[0];
        *(float4*)&hh[4]  = hp[1];
        *(float4*)&hh[8]  = hp[2];
        *(float4*)&hh[12] = hp[3];
#pragma unroll
        for (int k = 0; k < KNN; ++k)
            y[k] = fmaf(hh[k], w2dc, y[k]);
    }

    float acc = 0.f;
#pragma unroll
    for (int k = 0; k < KNN; ++k) {
        float gfv = f[((size_t)b * N + nidx[k]) * 64 + c];  // coalesced row
        acc = fmaf(y[k] + b2c, gfv, acc);
    }
    out[(size_t)gq * 64 + c] = acc * 0.25f;   // 1/sqrt(16)
}

extern "C" void kernel_launch(void* const* d_in, const int* in_sizes, int n_in,
                              void* d_out, int out_size, void* d_ws, size_t ws_size,
                              hipStream_t stream) {
    const float* feature1 = (const float*)d_in[0];
    const float* xyz1     = (const float*)d_in[1];
    const float* xyz2     = (const float*)d_in[2];
    const float* Wp       = (const float*)d_in[3];
    const float* bp       = (const float*)d_in[4];
    const float* W1       = (const float*)d_in[5];
    const float* b1       = (const float*)d_in[6];
    const float* W2       = (const float*)d_in[7];
    const float* b2       = (const float*)d_in[8];
    float* out = (float*)d_out;

    char* w = (char*)d_ws;
    float4*   spts   = (float4*)w;    w += (size_t)B * N * 16;
    float4*   squery = (float4*)w;    w += (size_t)B * M * 16;
    float*    f      = (float*)w;     w += (size_t)B * N * D * 4;
    int*      sidx   = (int*)w;       w += (size_t)B * N * 4;
    unsigned* pcount = (unsigned*)w;  w += (size_t)B * NC * 4;
    unsigned* qcount = (unsigned*)w;  w += (size_t)B * NSC * 4;
    unsigned* pstart = (unsigned*)w;  w += (size_t)B * NC * 4;
    unsigned* pcur   = (unsigned*)w;  w += (size_t)B * NC * 4;
    unsigned* qcur   = (unsigned*)w;  w += (size_t)B * NSC * 4;
    int*      wtab   = (int*)w;       w += (size_t)B * WTMAX * 4;
    int*      ntab   = (int*)w;       w += 16;
    int*      idxf   = (int*)w;       w += (size_t)KNN * BM * 4;
    float*    w_out  = out + (size_t)BM * D;

    // zero the two histogram arrays (contiguous)
    hipMemsetAsync(pcount, 0, (size_t)(B * NC + B * NSC) * 4, stream);

    k_count<<<BM / 256, 256, 0, stream>>>(xyz1, xyz2, pcount, qcount);
    k_scan<<<4, 256, 0, stream>>>(pcount, qcount, pstart, pcur, qcur, wtab, ntab);
    k_scatter<<<BM / 256, 256, 0, stream>>>(xyz1, xyz2, pcur, qcur, spts, sidx, squery);
    k_proj<<<B * N / 4, 256, 0, stream>>>(feature1, Wp, bp, f);
    k_knn<<<2 * WTMAX, 64, 0, stream>>>(spts, sidx, squery, pstart, pcount,
                                        wtab, ntab, idxf, w_out);
    k_final<<<BM / 4, 256, 0, stream>>>(xyz1, xyz2, f, idxf, W1, b1, W2, b2, out);
}

// Round 6
// 432.851 us; speedup vs baseline: 1.1619x; 1.1619x over previous
//
#include <hip/hip_runtime.h>
#include <math.h>

#define B 2
#define N 8192
#define M 8192
#define D 64
#define KNN 16
#define BM (B * M)           // 16384
#define GC 16                // grid cells per axis
#define NC (GC * GC * GC)    // 4096
#define NSC 64               // supercells (4x4x4)
#define WTMAX 192            // max wave-table entries per batch (proven bound)
#define NSL 8                // candidate slices (waves) per query group
#define CAP 24               // per-lane LDS candidate buffer slots
#define CUTR 0.135f          // filter radius cap (16-NN radius ~0.078)

// Sorted-insert of (dd,ii) into per-lane top-16 (v ascending). Strict < keeps
// earlier-inserted on exact ties.
#define CHAIN_INSERT(DVAL, IVAL) do {                                   \
    float _dd = (DVAL); int _ii = (IVAL);                               \
    _Pragma("unroll")                                                   \
    for (int _r = 0; _r < KNN; ++_r) {                                  \
        bool  _sm = _dd < v[_r];                                        \
        float _tv = v[_r]; int _ti = id[_r];                            \
        v[_r]  = _sm ? _dd : _tv;  id[_r] = _sm ? _ii : _ti;            \
        _dd    = _sm ? _tv : _dd;  _ii    = _sm ? _ti : _ii;            \
    }                                                                   \
} while (0)

// ---------------------------------------------------------------------------
// Kernel: histogram points into 4096 linear cells, queries into 64 supercells.
__global__ __launch_bounds__(256) void k_count(const float* __restrict__ xyz1,
                                               const float* __restrict__ xyz2,
                                               unsigned* __restrict__ pcount,
                                               unsigned* __restrict__ qcount) {
    int i = blockIdx.x * 256 + threadIdx.x;   // < B*N
    int b = i >> 13;
    const float* p = xyz1 + (size_t)i * 3;
    int cx = max(0, min(GC - 1, (int)(p[0] * GC)));
    int cy = max(0, min(GC - 1, (int)(p[1] * GC)));
    int cz = max(0, min(GC - 1, (int)(p[2] * GC)));
    atomicAdd(&pcount[b * NC + (cz * GC + cy) * GC + cx], 1u);
    const float* q = xyz2 + (size_t)i * 3;
    int qx = max(0, min(GC - 1, (int)(q[0] * GC)));
    int qy = max(0, min(GC - 1, (int)(q[1] * GC)));
    int qz = max(0, min(GC - 1, (int)(q[2] * GC)));
    int sc = ((qz >> 2) * 4 + (qy >> 2)) * 4 + (qx >> 2);
    atomicAdd(&qcount[b * NSC + sc], 1u);
}

// Kernel: blocks 0,1 = 4096-bin exclusive scan (points, per batch);
//         blocks 2,3 = 64-bin query scan + wave-table build (serial, tiny).
// wtab entry packs (sc<<21) | (qoff<<7) | qnum.
__global__ __launch_bounds__(256) void k_scan(const unsigned* __restrict__ pcount,
                                              const unsigned* __restrict__ qcount,
                                              unsigned* __restrict__ pstart,
                                              unsigned* __restrict__ pcur,
                                              unsigned* __restrict__ qcur,
                                              int* __restrict__ wtab,
                                              int* __restrict__ ntab) {
    __shared__ unsigned wsum[4];
    int blk = blockIdx.x;
    if (blk < 2) {
        int b = blk;
        int t = threadIdx.x;
        int base = b * NC + t * 16;
        unsigned c[16]; unsigned tsum = 0;
#pragma unroll
        for (int k = 0; k < 16; ++k) { c[k] = pcount[base + k]; tsum += c[k]; }
        int lane = t & 63, wv = t >> 6;
        unsigned x = tsum;
#pragma unroll
        for (int off = 1; off < 64; off <<= 1) {
            unsigned y = __shfl_up(x, off, 64);
            if (lane >= off) x += y;
        }
        if (lane == 63) wsum[wv] = x;
        __syncthreads();
        unsigned pre = 0;
        for (int k2 = 0; k2 < wv; ++k2) pre += wsum[k2];
        unsigned run = pre + x - tsum;
#pragma unroll
        for (int k = 0; k < 16; ++k) {
            pstart[base + k] = run; pcur[base + k] = run; run += c[k];
        }
    } else {
        int b = blk - 2;
        if (threadIdx.x != 0) return;
        int run = 0, nw = 0;
        for (int sc = 0; sc < NSC; ++sc) {
            int c = (int)qcount[b * NSC + sc];
            qcur[b * NSC + sc] = (unsigned)run;
            for (int o = 0; o < c; o += 64) {
                int num = min(64, c - o);
                wtab[b * WTMAX + nw++] = (sc << 21) | ((run + o) << 7) | num;
            }
            run += c;
        }
        ntab[b] = nw;
    }
}

// Kernel: scatter points (cell-sorted, with |p|^2) and queries (supercell-sorted).
__global__ __launch_bounds__(256) void k_scatter(const float* __restrict__ xyz1,
                                                 const float* __restrict__ xyz2,
                                                 unsigned* __restrict__ pcur,
                                                 unsigned* __restrict__ qcur,
                                                 float4* __restrict__ spts,
                                                 int* __restrict__ sidx,
                                                 float4* __restrict__ squery) {
    int i = blockIdx.x * 256 + threadIdx.x;   // < B*N
    int b = i >> 13;
    const float* p = xyz1 + (size_t)i * 3;
    float x = p[0], y = p[1], z = p[2];
    int cx = max(0, min(GC - 1, (int)(x * GC)));
    int cy = max(0, min(GC - 1, (int)(y * GC)));
    int cz = max(0, min(GC - 1, (int)(z * GC)));
    unsigned pos = atomicAdd(&pcur[b * NC + (cz * GC + cy) * GC + cx], 1u);
    spts[(size_t)b * N + pos] = make_float4(x, y, z, fmaf(x, x, fmaf(y, y, z * z)));
    sidx[(size_t)b * N + pos] = i & (N - 1);

    const float* q = xyz2 + (size_t)i * 3;
    float qx = q[0], qy = q[1], qz = q[2];
    int ax = max(0, min(GC - 1, (int)(qx * GC)));
    int ay = max(0, min(GC - 1, (int)(qy * GC)));
    int az = max(0, min(GC - 1, (int)(qz * GC)));
    int sc = ((az >> 2) * 4 + (ay >> 2)) * 4 + (ax >> 2);
    unsigned qpos = atomicAdd(&qcur[b * NSC + sc], 1u);
    squery[(size_t)b * M + qpos] = make_float4(qx, qy, qz, __int_as_float(i));
}

// Kernel: f = feature1 @ Wp + bp. Wave per row, lane = output channel.
__global__ __launch_bounds__(256) void k_proj(const float* __restrict__ feat,
                                              const float* __restrict__ Wp,
                                              const float* __restrict__ bp,
                                              float* __restrict__ f) {
    int c   = threadIdx.x & 63;
    int row = blockIdx.x * 4 + (threadIdx.x >> 6);   // 0..B*N-1
    const float* fr = feat + (size_t)row * 64;       // wave-uniform -> s_load
    float acc = bp[c];
#pragma unroll 8
    for (int d = 0; d < 64; ++d)
        acc = fmaf(fr[d], Wp[d * 64 + c], acc);
    f[(size_t)row * 64 + c] = acc;
}

// Kernel: grid KNN partials, slice-parallel. Block = 4 waves, each wave is one
// candidate slice s of a 64-query supercell group (8 slices over 2 blocks).
// Fixed box = supercell +/- 2 cells; wave scans rows rix % 8 == s with a tight
// filter loop (per-lane cut), buffers passers in LDS, drains once, writes a
// sorted 16-partial. Exactness enforced later in k_merge (cut check + fixup).
__global__ __launch_bounds__(256) void k_knn(const float4* __restrict__ spts,
                                             const float4* __restrict__ squery,
                                             const unsigned* __restrict__ pstart,
                                             const unsigned* __restrict__ pcount,
                                             const int* __restrict__ wtab,
                                             const int* __restrict__ ntab,
                                             float* __restrict__ part_d,
                                             int* __restrict__ part_i) {
    __shared__ float          fbuf[CAP][256];   // 24 KB, [slot][tid]
    __shared__ unsigned short ibuf[CAP][256];   // 12 KB
    int bid = blockIdx.x;
    int b   = bid / (WTMAX * 2);
    int rem = bid - b * (WTMAX * 2);
    int ti  = rem >> 1;
    int sq  = rem & 1;
    if (ti >= ntab[b]) return;
    int e = wtab[b * WTMAX + ti];
    int qnum = e & 127, qoff = (e >> 7) & 0x3FFF, sc = e >> 21;
    int tid = threadIdx.x;
    int lane = tid & 63;
    int s = sq * 4 + (tid >> 6);                // slice 0..7

    int sl = lane < qnum ? lane : qnum - 1;     // surplus lanes dup last query
    float4 q4 = squery[(size_t)b * M + qoff + sl];
    float qx = q4.x, qy = q4.y, qz = q4.z;
    float ax = -2.f * qx, ay = -2.f * qy, az = -2.f * qz;
    float q2 = fmaf(qx, qx, fmaf(qy, qy, qz * qz));

    int scx = sc & 3, scy = (sc >> 2) & 3, scz = sc >> 4;
    int ux0 = scx * 4 - 2, ux1 = scx * 4 + 5;   // unclipped box cells
    int uy0 = scy * 4 - 2, uy1 = scy * 4 + 5;
    int uz0 = scz * 4 - 2, uz1 = scz * 4 + 5;
    int bx0 = max(ux0, 0), bx1 = min(ux1, GC - 1);
    int by0 = max(uy0, 0), by1 = min(uy1, GC - 1);
    int bz0 = max(uz0, 0), bz1 = min(uz1, GC - 1);

    // per-lane distance to nearest unclipped box face (clipped faces -> inf)
    const float inv = 1.f / GC;
    float mxf = fminf(ux0 > 0      ? qx - ux0 * inv       : 1e30f,
                      ux1 < GC - 1 ? (ux1 + 1) * inv - qx : 1e30f);
    float myf = fminf(uy0 > 0      ? qy - uy0 * inv       : 1e30f,
                      uy1 < GC - 1 ? (uy1 + 1) * inv - qy : 1e30f);
    float mzf = fminf(uz0 > 0      ? qz - uz0 * inv       : 1e30f,
                      uz1 < GC - 1 ? (uz1 + 1) * inv - qz : 1e30f);
    float cut  = fminf(fminf(mxf, fminf(myf, mzf)), CUTR);
    float fcut = cut * cut - q2;                // filter in dv = d^2 - q^2 space

    float v[KNN]; int id[KNN];
#pragma unroll
    for (int r = 0; r < KNN; ++r) { v[r] = 3.4e38f; id[r] = 0; }
    int cnt = 0;
    int pb = b * N, cb = b * NC;
    int xspan = bx1 - bx0;

    int rix = 0;
    for (int zz = bz0; zz <= bz1; ++zz)
        for (int yy = by0; yy <= by1; ++yy, ++rix) {
            if ((rix & 7) != s) continue;       // this wave's rows only
            int codeL = cb + (zz * GC + yy) * GC + bx0;   // uniform
            int st = (int)pstart[codeL];
            int en = (int)pstart[codeL + xspan] + (int)pcount[codeL + xspan];
#pragma unroll 4
            for (int t = st; t < en; ++t) {
                float4 p = spts[pb + t];        // uniform -> s_load_dwordx4
                float dv = fmaf(ax, p.x, p.w);
                dv = fmaf(ay, p.y, dv);
                dv = fmaf(az, p.z, dv);
                if (dv < fcut) {
                    if (cnt < CAP) {
                        fbuf[cnt][tid] = dv;
                        ibuf[cnt][tid] = (unsigned short)t;
                        ++cnt;
                    } else {                    // overflow (P ~ 1e-5)
                        CHAIN_INSERT(dv, t);
                    }
                }
            }
        }

    // drain: each lane chain-inserts its buffered candidates
    int mx = cnt;
#pragma unroll
    for (int off = 32; off; off >>= 1)
        mx = max(mx, __shfl_xor(mx, off, 64));
    mx = __builtin_amdgcn_readfirstlane(mx);
    for (int t2 = 0; t2 < mx; ++t2) {
        float dv = fbuf[t2][tid];
        int jj = ibuf[t2][tid];
        if (t2 < cnt && dv < v[KNN - 1]) CHAIN_INSERT(dv, jj);
    }

    if (lane < qnum) {
        int col = b * M + qoff + lane;          // sorted-query column
#pragma unroll
        for (int r = 0; r < KNN; ++r) {
            part_d[(size_t)(s * KNN + r) * BM + col] = v[r];
            part_i[(size_t)(s * KNN + r) * BM + col] = id[r];
        }
    }
}

// Kernel: merge 8x16 partials per sorted query (2-stage, coalesced), emit
// final idx + weight; verify exactness bound, else push to miss-list.
__global__ __launch_bounds__(256) void k_merge(const float4* __restrict__ squery,
                                               const float* __restrict__ part_d,
                                               const int* __restrict__ part_i,
                                               const int* __restrict__ sidx,
                                               int* __restrict__ idx_out,
                                               float* __restrict__ w_out,
                                               int* __restrict__ misscnt,
                                               int* __restrict__ misslist) {
    __shared__ float sd[4][KNN][64];    // 16 KB
    __shared__ int   si[4][KNN][64];    // 16 KB
    int ql  = threadIdx.x & 63;
    int sub = threadIdx.x >> 6;
    int sqid = blockIdx.x * 64 + ql;    // 0..BM-1
    int b = sqid >> 13;

    float v[KNN]; int id[KNN];
#pragma unroll
    for (int r = 0; r < KNN; ++r) { v[r] = 3.4e38f; id[r] = 0; }

#pragma unroll 4
    for (int e = sub * 32; e < sub * 32 + 32; ++e) {
        float dv = part_d[(size_t)e * BM + sqid];      // coalesced
        if (dv < v[KNN - 1]) {
            int ii = part_i[(size_t)e * BM + sqid];
            CHAIN_INSERT(dv, ii);
        }
    }
#pragma unroll
    for (int r = 0; r < KNN; ++r) { sd[sub][r][ql] = v[r]; si[sub][r][ql] = id[r]; }
    __syncthreads();
    if (sub != 0) return;

    for (int e = KNN; e < 4 * KNN; ++e) {
        float dv = sd[e >> 4][e & 15][ql];
        if (dv < v[KNN - 1]) CHAIN_INSERT(dv, si[e >> 4][e & 15][ql]);
    }

    float4 q4 = squery[sqid];
    float qx = q4.x, qy = q4.y, qz = q4.z;
    int gq = __float_as_int(q4.w);
    float q2 = fmaf(qx, qx, fmaf(qy, qy, qz * qz));

    // recompute the per-query cut (must match k_knn's formula)
    int cx = max(0, min(GC - 1, (int)(qx * GC))) >> 2;
    int cy = max(0, min(GC - 1, (int)(qy * GC))) >> 2;
    int cz = max(0, min(GC - 1, (int)(qz * GC))) >> 2;
    int ux0 = cx * 4 - 2, ux1 = cx * 4 + 5;
    int uy0 = cy * 4 - 2, uy1 = cy * 4 + 5;
    int uz0 = cz * 4 - 2, uz1 = cz * 4 + 5;
    const float inv = 1.f / GC;
    float mxf = fminf(ux0 > 0      ? qx - ux0 * inv       : 1e30f,
                      ux1 < GC - 1 ? (ux1 + 1) * inv - qx : 1e30f);
    float myf = fminf(uy0 > 0      ? qy - uy0 * inv       : 1e30f,
                      uy1 < GC - 1 ? (uy1 + 1) * inv - qy : 1e30f);
    float mzf = fminf(uz0 > 0      ? qz - uz0 * inv       : 1e30f,
                      uz1 < GC - 1 ? (uz1 + 1) * inv - qz : 1e30f);
    float cut = fminf(fminf(mxf, fminf(myf, mzf)), CUTR);

    w_out[gq] = (v[0] + q2 > 0.03f) ? 10.0f : 1.0f;
#pragma unroll
    for (int r = 0; r < KNN; ++r)
        idx_out[(size_t)r * BM + gq] = sidx[b * N + id[r]];

    if (!(v[KNN - 1] + q2 < cut * cut * 0.9999f)) {    // exactness check
        int slot = atomicAdd(misscnt, 1);
        misslist[slot] = sqid;
    }
}

// Kernel: brute-force fixup for missed queries (normally zero work).
__global__ __launch_bounds__(64) void k_fix(const float4* __restrict__ spts,
                                            const int* __restrict__ sidx,
                                            const float4* __restrict__ squery,
                                            const int* __restrict__ misscnt,
                                            const int* __restrict__ misslist,
                                            int* __restrict__ idx_out,
                                            float* __restrict__ w_out) {
    __shared__ float md[64 * KNN];
    __shared__ int   mi[64 * KNN];
    if ((int)blockIdx.x >= *misscnt) return;
    int sqid = misslist[blockIdx.x];
    int b = sqid >> 13;
    int lane = threadIdx.x;
    float4 q4 = squery[sqid];
    float qx = q4.x, qy = q4.y, qz = q4.z;
    float ax = -2.f * qx, ay = -2.f * qy, az = -2.f * qz;
    float q2 = fmaf(qx, qx, fmaf(qy, qy, qz * qz));

    float v[KNN]; int id[KNN];
#pragma unroll
    for (int r = 0; r < KNN; ++r) { v[r] = 3.4e38f; id[r] = 0; }
    for (int t = lane; t < N; t += 64) {
        float4 p = spts[(size_t)b * N + t];
        float dv = fmaf(ax, p.x, p.w);
        dv = fmaf(ay, p.y, dv);
        dv = fmaf(az, p.z, dv);
        if (dv < v[KNN - 1]) CHAIN_INSERT(dv, t);
    }
#pragma unroll
    for (int r = 0; r < KNN; ++r) { md[lane * KNN + r] = v[r]; mi[lane * KNN + r] = id[r]; }
    __syncthreads();
    if (lane != 0) return;
#pragma unroll
    for (int r = 0; r < KNN; ++r) { v[r] = 3.4e38f; id[r] = 0; }
    for (int e2 = 0; e2 < 64 * KNN; ++e2) {
        float dv = md[e2];
        if (dv < v[KNN - 1]) CHAIN_INSERT(dv, mi[e2]);
    }
    int gq = __float_as_int(q4.w);
    w_out[gq] = (v[0] + q2 > 0.03f) ? 10.0f : 1.0f;
#pragma unroll
    for (int r = 0; r < KNN; ++r)
        idx_out[(size_t)r * BM + gq] = sidx[b * N + id[r]];
}

// Kernel: gather + MLP + reduce. One wave per query, lane = channel c.
__global__ __launch_bounds__(256) void k_final(const float* __restrict__ xyz1,
                                               const float* __restrict__ xyz2,
                                               const float* __restrict__ f,
                                               const int* __restrict__ idx,
                                               const float* __restrict__ W1,
                                               const float* __restrict__ b1,
                                               const float* __restrict__ W2,
                                               const float* __restrict__ b2,
                                               float* __restrict__ out) {
    __shared__ float w2s[64 * 64];      // 16 KB, [d][c]
    __shared__ float hT[4][64 * 16];    // 16 KB, per-wave [d][k]

    for (int t = threadIdx.x; t < 64 * 16; t += 256)
        ((float4*)w2s)[t] = ((const float4*)W2)[t];

    int wv = threadIdx.x >> 6;
    int c  = threadIdx.x & 63;
    int gq = blockIdx.x * 4 + wv;
    int b  = gq >> 13;

    const float* q = xyz2 + (size_t)gq * 3;
    float qx = q[0], qy = q[1], qz = q[2];
    float w10 = W1[c], w11 = W1[64 + c], w12 = W1[128 + c];
    float b1c = b1[c], b2c = b2[c];

    int nidx[KNN];
#pragma unroll
    for (int k = 0; k < KNN; ++k)
        nidx[k] = idx[(size_t)k * BM + gq];      // wave-broadcast load

    float h[KNN];
#pragma unroll
    for (int k = 0; k < KNN; ++k) {
        const float* p = xyz1 + ((size_t)b * N + nidx[k]) * 3;
        float gx = p[0] - qx, gy = p[1] - qy, gz = p[2] - qz;
        float t = fmaf(gx, w10, b1c);
        t = fmaf(gy, w11, t);
        t = fmaf(gz, w12, t);
        h[k] = fmaxf(t, 0.f);
    }

#pragma unroll
    for (int k = 0; k < KNN; k += 4)
        *(float4*)&hT[wv][c * 16 + k] = make_float4(h[k], h[k+1], h[k+2], h[k+3]);

    __syncthreads();   // covers W2 staging + hT visibility

    float y[KNN];
#pragma unroll
    for (int k = 0; k < KNN; ++k) y[k] = 0.f;

#pragma unroll 4
    for (int d = 0; d < 64; ++d) {
        float w2dc = w2s[d * 64 + c];                       // conflict-free
        const float4* hp = (const float4*)&hT[wv][d * 16];  // broadcast reads
        float hh[16];
        *(float4*)&hh[0]  = hp[0];
        *(float4*)&hh[4]  = hp[1];
        *(float4*)&hh[8]  = hp[2];
        *(float4*)&hh[12] = hp[3];
#pragma unroll
        for (int k = 0; k < KNN; ++k)
            y[k] = fmaf(hh[k], w2dc, y[k]);
    }

    float acc = 0.f;
#pragma unroll
    for (int k = 0; k < KNN; ++k) {
        float gfv = f[((size_t)b * N + nidx[k]) * 64 + c];  // coalesced row
        acc = fmaf(y[k] + b2c, gfv, acc);
    }
    out[(size_t)gq * 64 + c] = acc * 0.25f;   // 1/sqrt(16)
}

extern "C" void kernel_launch(void* const* d_in, const int* in_sizes, int n_in,
                              void* d_out, int out_size, void* d_ws, size_t ws_size,
                              hipStream_t stream) {
    const float* feature1 = (const float*)d_in[0];
    const float* xyz1     = (const float*)d_in[1];
    const float* xyz2     = (const float*)d_in[2];
    const float* Wp       = (const float*)d_in[3];
    const float* bp       = (const float*)d_in[4];
    const float* W1       = (const float*)d_in[5];
    const float* b1       = (const float*)d_in[6];
    const float* W2       = (const float*)d_in[7];
    const float* b2       = (const float*)d_in[8];
    float* out = (float*)d_out;

    char* w = (char*)d_ws;
    float4*   spts   = (float4*)w;    w += (size_t)B * N * 16;
    float4*   squery = (float4*)w;    w += (size_t)B * M * 16;
    float*    f      = (float*)w;     w += (size_t)B * N * D * 4;
    int*      sidx   = (int*)w;       w += (size_t)B * N * 4;
    unsigned* pcount = (unsigned*)w;  w += (size_t)B * NC * 4;
    unsigned* qcount = (unsigned*)w;  w += (size_t)B * NSC * 4;
    int*      misscnt= (int*)w;       w += 16;
    unsigned* pstart = (unsigned*)w;  w += (size_t)B * NC * 4;
    unsigned* pcur   = (unsigned*)w;  w += (size_t)B * NC * 4;
    unsigned* qcur   = (unsigned*)w;  w += (size_t)B * NSC * 4;
    int*      wtab   = (int*)w;       w += (size_t)B * WTMAX * 4;
    int*      ntab   = (int*)w;       w += 16;
    float*    partd  = (float*)w;     w += (size_t)NSL * KNN * BM * 4;
    int*      parti  = (int*)w;       w += (size_t)NSL * KNN * BM * 4;
    int*      misslist=(int*)w;       w += (size_t)BM * 4;
    int*      idxf   = (int*)w;       w += (size_t)KNN * BM * 4;
    float*    w_out  = out + (size_t)BM * D;

    // zero pcount + qcount + misscnt (contiguous)
    hipMemsetAsync(pcount, 0, (size_t)(B * NC + B * NSC) * 4 + 16, stream);

    k_count<<<BM / 256, 256, 0, stream>>>(xyz1, xyz2, pcount, qcount);
    k_scan<<<4, 256, 0, stream>>>(pcount, qcount, pstart, pcur, qcur, wtab, ntab);
    k_scatter<<<BM / 256, 256, 0, stream>>>(xyz1, xyz2, pcur, qcur, spts, sidx, squery);
    k_proj<<<B * N / 4, 256, 0, stream>>>(feature1, Wp, bp, f);
    k_knn<<<B * WTMAX * 2, 256, 0, stream>>>(spts, squery, pstart, pcount,
                                             wtab, ntab, partd, parti);
    k_merge<<<BM / 64, 256, 0, stream>>>(squery, partd, parti, sidx,
                                         idxf, w_out, misscnt, misslist);
    k_fix<<<128, 64, 0, stream>>>(spts, sidx, squery, misscnt, misslist, idxf, w_out);
    k_final<<<BM / 4, 256, 0, stream>>>(xyz1, xyz2, f, idxf, W1, b1, W2, b2, out);
}

// Round 7
// 293.166 us; speedup vs baseline: 1.7156x; 1.4765x over previous
//
#include <hip/hip_runtime.h>
#include <math.h>

#define B 2
#define N 8192
#define M 8192
#define D 64
#define KNN 16
#define BM (B * M)           // 16384
#define GC 16                // grid cells per axis
#define NC (GC * GC * GC)    // 4096
#define NSC 64               // supercells (4x4x4)
#define WTMAX 192            // max wave-table entries per batch (proven bound)
#define NSL 8                // candidate slices (waves) per query group
#define CAP 24               // per-lane LDS candidate buffer slots

// Per-query filter radius: lambda~60 expected in-(clipped-)ball candidates.
// nc = #axes within 0.16 of a domain wall (density octant compensation).
// MUST be recomputed identically in k_knn and k_merge.
__device__ __forceinline__ float query_cutr(float qx, float qy, float qz) {
    int nc = ((qx < 0.16f) | (qx > 0.84f)) + ((qy < 0.16f) | (qy > 0.84f))
           + ((qz < 0.16f) | (qz > 0.84f));
    return nc == 0 ? 0.121f : nc == 1 ? 0.1525f : nc == 2 ? 0.1921f : 0.242f;
}

// Sorted-insert of (dd,ii) into per-lane top-16 (v ascending). Strict < keeps
// earlier-inserted on exact ties.
#define CHAIN_INSERT(DVAL, IVAL) do {                                   \
    float _dd = (DVAL); int _ii = (IVAL);                               \
    _Pragma("unroll")                                                   \
    for (int _r = 0; _r < KNN; ++_r) {                                  \
        bool  _sm = _dd < v[_r];                                        \
        float _tv = v[_r]; int _ti = id[_r];                            \
        v[_r]  = _sm ? _dd : _tv;  id[_r] = _sm ? _ii : _ti;            \
        _dd    = _sm ? _tv : _dd;  _ii    = _sm ? _ti : _ii;            \
    }                                                                   \
} while (0)

// ---------------------------------------------------------------------------
// Kernel: histogram points into 4096 linear cells, queries into 64 supercells.
__global__ __launch_bounds__(256) void k_count(const float* __restrict__ xyz1,
                                               const float* __restrict__ xyz2,
                                               unsigned* __restrict__ pcount,
                                               unsigned* __restrict__ qcount) {
    int i = blockIdx.x * 256 + threadIdx.x;   // < B*N
    int b = i >> 13;
    const float* p = xyz1 + (size_t)i * 3;
    int cx = max(0, min(GC - 1, (int)(p[0] * GC)));
    int cy = max(0, min(GC - 1, (int)(p[1] * GC)));
    int cz = max(0, min(GC - 1, (int)(p[2] * GC)));
    atomicAdd(&pcount[b * NC + (cz * GC + cy) * GC + cx], 1u);
    const float* q = xyz2 + (size_t)i * 3;
    int qx = max(0, min(GC - 1, (int)(q[0] * GC)));
    int qy = max(0, min(GC - 1, (int)(q[1] * GC)));
    int qz = max(0, min(GC - 1, (int)(q[2] * GC)));
    int sc = ((qz >> 2) * 4 + (qy >> 2)) * 4 + (qx >> 2);
    atomicAdd(&qcount[b * NSC + sc], 1u);
}

// Kernel: blocks 0,1 = 4096-bin exclusive scan (points, per batch);
//         blocks 2,3 = 64-bin query scan + wave-table build (serial, tiny).
// wtab entry packs (qoff<<7) | qnum.
__global__ __launch_bounds__(256) void k_scan(const unsigned* __restrict__ pcount,
                                              const unsigned* __restrict__ qcount,
                                              unsigned* __restrict__ pstart,
                                              unsigned* __restrict__ pcur,
                                              unsigned* __restrict__ qcur,
                                              int* __restrict__ wtab,
                                              int* __restrict__ ntab) {
    __shared__ unsigned wsum[4];
    int blk = blockIdx.x;
    if (blk < 2) {
        int b = blk;
        int t = threadIdx.x;
        int base = b * NC + t * 16;
        unsigned c[16]; unsigned tsum = 0;
#pragma unroll
        for (int k = 0; k < 16; ++k) { c[k] = pcount[base + k]; tsum += c[k]; }
        int lane = t & 63, wv = t >> 6;
        unsigned x = tsum;
#pragma unroll
        for (int off = 1; off < 64; off <<= 1) {
            unsigned y = __shfl_up(x, off, 64);
            if (lane >= off) x += y;
        }
        if (lane == 63) wsum[wv] = x;
        __syncthreads();
        unsigned pre = 0;
        for (int k2 = 0; k2 < wv; ++k2) pre += wsum[k2];
        unsigned run = pre + x - tsum;
#pragma unroll
        for (int k = 0; k < 16; ++k) {
            pstart[base + k] = run; pcur[base + k] = run; run += c[k];
        }
    } else {
        int b = blk - 2;
        if (threadIdx.x != 0) return;
        int run = 0, nw = 0;
        for (int sc = 0; sc < NSC; ++sc) {
            int c = (int)qcount[b * NSC + sc];
            qcur[b * NSC + sc] = (unsigned)run;
            for (int o = 0; o < c; o += 64) {
                int num = min(64, c - o);
                wtab[b * WTMAX + nw++] = ((run + o) << 7) | num;
            }
            run += c;
        }
        ntab[b] = nw;
    }
}

// Kernel: scatter points (cell-sorted, with |p|^2) and queries (supercell-sorted).
__global__ __launch_bounds__(256) void k_scatter(const float* __restrict__ xyz1,
                                                 const float* __restrict__ xyz2,
                                                 unsigned* __restrict__ pcur,
                                                 unsigned* __restrict__ qcur,
                                                 float4* __restrict__ spts,
                                                 int* __restrict__ sidx,
                                                 float4* __restrict__ squery) {
    int i = blockIdx.x * 256 + threadIdx.x;   // < B*N
    int b = i >> 13;
    const float* p = xyz1 + (size_t)i * 3;
    float x = p[0], y = p[1], z = p[2];
    int cx = max(0, min(GC - 1, (int)(x * GC)));
    int cy = max(0, min(GC - 1, (int)(y * GC)));
    int cz = max(0, min(GC - 1, (int)(z * GC)));
    unsigned pos = atomicAdd(&pcur[b * NC + (cz * GC + cy) * GC + cx], 1u);
    spts[(size_t)b * N + pos] = make_float4(x, y, z, fmaf(x, x, fmaf(y, y, z * z)));
    sidx[(size_t)b * N + pos] = i & (N - 1);

    const float* q = xyz2 + (size_t)i * 3;
    float qx = q[0], qy = q[1], qz = q[2];
    int ax = max(0, min(GC - 1, (int)(qx * GC)));
    int ay = max(0, min(GC - 1, (int)(qy * GC)));
    int az = max(0, min(GC - 1, (int)(qz * GC)));
    int sc = ((az >> 2) * 4 + (ay >> 2)) * 4 + (ax >> 2);
    unsigned qpos = atomicAdd(&qcur[b * NSC + sc], 1u);
    squery[(size_t)b * M + qpos] = make_float4(qx, qy, qz, __int_as_float(i));
}

// Kernel: f = feature1 @ Wp + bp. Wave per row, lane = output channel.
__global__ __launch_bounds__(256) void k_proj(const float* __restrict__ feat,
                                              const float* __restrict__ Wp,
                                              const float* __restrict__ bp,
                                              float* __restrict__ f) {
    int c   = threadIdx.x & 63;
    int row = blockIdx.x * 4 + (threadIdx.x >> 6);   // 0..B*N-1
    const float* fr = feat + (size_t)row * 64;       // wave-uniform -> s_load
    float acc = bp[c];
#pragma unroll 8
    for (int d = 0; d < 64; ++d)
        acc = fmaf(fr[d], Wp[d * 64 + c], acc);
    f[(size_t)row * 64 + c] = acc;
}

// Kernel: grid KNN partials, slice-parallel. Block = 4 waves; each wave = one
// of 8 candidate slices of a 64-query group (2 blocks per group).
// Box = wave-reduced bbox of [q - cutr, q + cutr] over the group's queries
// (rounded out to cells) => every per-query filter ball is fully scanned.
// Wave scans rows rix % 8 == s; per-lane filter (d^2 < cutr^2), passers
// buffered in conflict-free LDS, one drain, sorted 16-partial out.
__global__ __launch_bounds__(256) void k_knn(const float4* __restrict__ spts,
                                             const float4* __restrict__ squery,
                                             const unsigned* __restrict__ pstart,
                                             const unsigned* __restrict__ pcount,
                                             const int* __restrict__ wtab,
                                             const int* __restrict__ ntab,
                                             float* __restrict__ part_d,
                                             int* __restrict__ part_i) {
    __shared__ float          fbuf[CAP][256];   // 24 KB, [slot][tid]
    __shared__ unsigned short ibuf[CAP][256];   // 12 KB
    int bid = blockIdx.x;
    int b   = bid / (WTMAX * 2);
    int rem = bid - b * (WTMAX * 2);
    int ti  = rem >> 1;
    int sq  = rem & 1;
    if (ti >= ntab[b]) return;
    int e = wtab[b * WTMAX + ti];
    int qnum = e & 127, qoff = (e >> 7) & 0x3FFF;
    int tid = threadIdx.x;
    int lane = tid & 63;
    int s = sq * 4 + (tid >> 6);                // slice 0..7

    int sl = lane < qnum ? lane : qnum - 1;     // surplus lanes dup last query
    float4 q4 = squery[(size_t)b * M + qoff + sl];
    float qx = q4.x, qy = q4.y, qz = q4.z;
    float ax = -2.f * qx, ay = -2.f * qy, az = -2.f * qz;
    float q2 = fmaf(qx, qx, fmaf(qy, qy, qz * qz));
    float cutr = query_cutr(qx, qy, qz);
    float fcut = cutr * cutr - q2;              // filter in dv = d^2 - q^2 space

    // per-lane cell box of the filter ball, then wave-reduced group box
    int lx0 = max(0, (int)floorf((qx - cutr) * GC));
    int lx1 = min(GC - 1, (int)floorf((qx + cutr) * GC));
    int ly0 = max(0, (int)floorf((qy - cutr) * GC));
    int ly1 = min(GC - 1, (int)floorf((qy + cutr) * GC));
    int lz0 = max(0, (int)floorf((qz - cutr) * GC));
    int lz1 = min(GC - 1, (int)floorf((qz + cutr) * GC));
#pragma unroll
    for (int off = 1; off < 64; off <<= 1) {
        lx0 = min(lx0, __shfl_xor(lx0, off, 64));
        lx1 = max(lx1, __shfl_xor(lx1, off, 64));
        ly0 = min(ly0, __shfl_xor(ly0, off, 64));
        ly1 = max(ly1, __shfl_xor(ly1, off, 64));
        lz0 = min(lz0, __shfl_xor(lz0, off, 64));
        lz1 = max(lz1, __shfl_xor(lz1, off, 64));
    }
    int bx0 = __builtin_amdgcn_readfirstlane(lx0);
    int bx1 = __builtin_amdgcn_readfirstlane(lx1);
    int by0 = __builtin_amdgcn_readfirstlane(ly0);
    int by1 = __builtin_amdgcn_readfirstlane(ly1);
    int bz0 = __builtin_amdgcn_readfirstlane(lz0);
    int bz1 = __builtin_amdgcn_readfirstlane(lz1);

    float v[KNN]; int id[KNN];
#pragma unroll
    for (int r = 0; r < KNN; ++r) { v[r] = 3.4e38f; id[r] = 0; }
    int cnt = 0;
    int pb = b * N, cb = b * NC;
    int xspan = bx1 - bx0;

    int rix = 0;
    for (int zz = bz0; zz <= bz1; ++zz)
        for (int yy = by0; yy <= by1; ++yy, ++rix) {
            if ((rix & 7) != s) continue;       // this wave's rows only
            int codeL = cb + (zz * GC + yy) * GC + bx0;   // uniform
            int st = (int)pstart[codeL];
            int en = (int)pstart[codeL + xspan] + (int)pcount[codeL + xspan];
#pragma unroll 4
            for (int t = st; t < en; ++t) {
                float4 p = spts[pb + t];        // uniform -> s_load_dwordx4
                float dv = fmaf(ax, p.x, p.w);
                dv = fmaf(ay, p.y, dv);
                dv = fmaf(az, p.z, dv);
                if (dv < fcut) {
                    if (cnt < CAP) {
                        fbuf[cnt][tid] = dv;
                        ibuf[cnt][tid] = (unsigned short)t;
                        ++cnt;
                    } else {                    // overflow (rare tail)
                        CHAIN_INSERT(dv, t);
                    }
                }
            }
        }

    // drain: each lane chain-inserts its buffered candidates
    int mx = cnt;
#pragma unroll
    for (int off = 32; off; off >>= 1)
        mx = max(mx, __shfl_xor(mx, off, 64));
    mx = __builtin_amdgcn_readfirstlane(mx);
    for (int t2 = 0; t2 < mx; ++t2) {
        float dv = fbuf[t2][tid];
        int jj = ibuf[t2][tid];
        if (t2 < cnt && dv < v[KNN - 1]) CHAIN_INSERT(dv, jj);
    }

    if (lane < qnum) {
        int col = b * M + qoff + lane;          // sorted-query column
#pragma unroll
        for (int r = 0; r < KNN; ++r) {
            part_d[(size_t)(s * KNN + r) * BM + col] = v[r];
            part_i[(size_t)(s * KNN + r) * BM + col] = id[r];
        }
    }
}

// Kernel: merge 8x16 partials per sorted query (2-stage, coalesced), emit
// final idx + weight; verify exactness bound (d16 < cutr), else miss-list.
__global__ __launch_bounds__(256) void k_merge(const float4* __restrict__ squery,
                                               const float* __restrict__ part_d,
                                               const int* __restrict__ part_i,
                                               const int* __restrict__ sidx,
                                               int* __restrict__ idx_out,
                                               float* __restrict__ w_out,
                                               int* __restrict__ misscnt,
                                               int* __restrict__ misslist) {
    __shared__ float sd[4][KNN][64];    // 16 KB
    __shared__ int   si[4][KNN][64];    // 16 KB
    int ql  = threadIdx.x & 63;
    int sub = threadIdx.x >> 6;
    int sqid = blockIdx.x * 64 + ql;    // 0..BM-1
    int b = sqid >> 13;

    float v[KNN]; int id[KNN];
#pragma unroll
    for (int r = 0; r < KNN; ++r) { v[r] = 3.4e38f; id[r] = 0; }

#pragma unroll 4
    for (int e = sub * 32; e < sub * 32 + 32; ++e) {
        float dv = part_d[(size_t)e * BM + sqid];      // coalesced
        if (dv < v[KNN - 1]) {
            int ii = part_i[(size_t)e * BM + sqid];
            CHAIN_INSERT(dv, ii);
        }
    }
#pragma unroll
    for (int r = 0; r < KNN; ++r) { sd[sub][r][ql] = v[r]; si[sub][r][ql] = id[r]; }
    __syncthreads();
    if (sub != 0) return;

    for (int e = KNN; e < 4 * KNN; ++e) {
        float dv = sd[e >> 4][e & 15][ql];
        if (dv < v[KNN - 1]) CHAIN_INSERT(dv, si[e >> 4][e & 15][ql]);
    }

    float4 q4 = squery[sqid];
    float qx = q4.x, qy = q4.y, qz = q4.z;
    int gq = __float_as_int(q4.w);
    float q2 = fmaf(qx, qx, fmaf(qy, qy, qz * qz));
    float cutr = query_cutr(qx, qy, qz);

    w_out[gq] = (v[0] + q2 > 0.03f) ? 10.0f : 1.0f;
#pragma unroll
    for (int r = 0; r < KNN; ++r)
        idx_out[(size_t)r * BM + gq] = sidx[b * N + id[r]];

    if (!(v[KNN - 1] + q2 < cutr * cutr * 0.9999f)) {  // exactness check
        int slot = atomicAdd(misscnt, 1);
        misslist[slot] = sqid;
    }
}

// Kernel: brute-force fixup for missed queries (normally zero work).
// One wave per query (grid-stride): per-lane top-16 over N/64 points, then a
// cross-lane bitonic tournament merge (6 rounds) -> global top-16 on all lanes.
__global__ __launch_bounds__(64) void k_fix(const float4* __restrict__ spts,
                                            const int* __restrict__ sidx,
                                            const float4* __restrict__ squery,
                                            const int* __restrict__ misscnt,
                                            const int* __restrict__ misslist,
                                            int* __restrict__ idx_out,
                                            float* __restrict__ w_out) {
    int lane = threadIdx.x;
    int nmiss = misscnt[0];
    for (int qi = blockIdx.x; qi < nmiss; qi += 64) {
        int sqid = misslist[qi];
        int b = sqid >> 13;
        float4 q4 = squery[sqid];
        float qx = q4.x, qy = q4.y, qz = q4.z;
        float ax = -2.f * qx, ay = -2.f * qy, az = -2.f * qz;
        float q2 = fmaf(qx, qx, fmaf(qy, qy, qz * qz));

        float v[KNN]; int id[KNN];
#pragma unroll
        for (int r = 0; r < KNN; ++r) { v[r] = 3.4e38f; id[r] = 0; }
        for (int t = lane; t < N; t += 64) {
            float4 p = spts[(size_t)b * N + t];
            float dv = fmaf(ax, p.x, p.w);
            dv = fmaf(ay, p.y, dv);
            dv = fmaf(az, p.z, dv);
            if (dv < v[KNN - 1]) CHAIN_INSERT(dv, t);
        }
        // bitonic tournament: after 6 rounds every lane holds global top-16
#pragma unroll
        for (int rd = 0; rd < 6; ++rd) {
            int dl = 1 << rd;
            float nv[KNN]; int nid[KNN];
#pragma unroll
            for (int i = 0; i < KNN; ++i) {          // half-cleaner vs partner
                float pv = __shfl_xor(v[KNN - 1 - i], dl, 64);
                int   pi = __shfl_xor(id[KNN - 1 - i], dl, 64);
                bool take = v[i] <= pv;
                nv[i]  = take ? v[i] : pv;
                nid[i] = take ? id[i] : pi;
            }
#pragma unroll
            for (int st = 8; st; st >>= 1) {         // sort bitonic 16-seq
#pragma unroll
                for (int i = 0; i < KNN; ++i) {
                    if (!(i & st)) {
                        int j = i | st;
                        bool sw = nv[i] > nv[j];
                        float ta = sw ? nv[j] : nv[i];
                        float tb = sw ? nv[i] : nv[j];
                        int ia = sw ? nid[j] : nid[i];
                        int ib = sw ? nid[i] : nid[j];
                        nv[i] = ta; nv[j] = tb; nid[i] = ia; nid[j] = ib;
                    }
                }
            }
#pragma unroll
            for (int i = 0; i < KNN; ++i) { v[i] = nv[i]; id[i] = nid[i]; }
        }
        if (lane == 0) {
            int gq = __float_as_int(q4.w);
            w_out[gq] = (v[0] + q2 > 0.03f) ? 10.0f : 1.0f;
#pragma unroll
            for (int r = 0; r < KNN; ++r)
                idx_out[(size_t)r * BM + gq] = sidx[b * N + id[r]];
        }
    }
}

// Kernel: gather + MLP + reduce. One wave per query, lane = channel c.
__global__ __launch_bounds__(256) void k_final(const float* __restrict__ xyz1,
                                               const float* __restrict__ xyz2,
                                               const float* __restrict__ f,
                                               const int* __restrict__ idx,
                                               const float* __restrict__ W1,
                                               const float* __restrict__ b1,
                                               const float* __restrict__ W2,
                                               const float* __restrict__ b2,
                                               float* __restrict__ out) {
    __shared__ float w2s[64 * 64];      // 16 KB, [d][c]
    __shared__ float hT[4][64 * 16];    // 16 KB, per-wave [d][k]

    for (int t = threadIdx.x; t < 64 * 16; t += 256)
        ((float4*)w2s)[t] = ((const float4*)W2)[t];

    int wv = threadIdx.x >> 6;
    int c  = threadIdx.x & 63;
    int gq = blockIdx.x * 4 + wv;
    int b  = gq >> 13;

    const float* q = xyz2 + (size_t)gq * 3;
    float qx = q[0], qy = q[1], qz = q[2];
    float w10 = W1[c], w11 = W1[64 + c], w12 = W1[128 + c];
    float b1c = b1[c], b2c = b2[c];

    int nidx[KNN];
#pragma unroll
    for (int k = 0; k < KNN; ++k)
        nidx[k] = idx[(size_t)k * BM + gq];      // wave-broadcast load

    float h[KNN];
#pragma unroll
    for (int k = 0; k < KNN; ++k) {
        const float* p = xyz1 + ((size_t)b * N + nidx[k]) * 3;
        float gx = p[0] - qx, gy = p[1] - qy, gz = p[2] - qz;
        float t = fmaf(gx, w10, b1c);
        t = fmaf(gy, w11, t);
        t = fmaf(gz, w12, t);
        h[k] = fmaxf(t, 0.f);
    }

#pragma unroll
    for (int k = 0; k < KNN; k += 4)
        *(float4*)&hT[wv][c * 16 + k] = make_float4(h[k], h[k+1], h[k+2], h[k+3]);

    __syncthreads();   // covers W2 staging + hT visibility

    float y[KNN];
#pragma unroll
    for (int k = 0; k < KNN; ++k) y[k] = 0.f;

#pragma unroll 4
    for (int d = 0; d < 64; ++d) {
        float w2dc = w2s[d * 64 + c];                       // conflict-free
        const float4* hp = (const float4*)&hT[wv][d * 16];  // broadcast reads
        float hh[16];
        *(float4*)&hh[0]  = hp[0];
        *(float4*)&hh[4]  = hp[1];
        *(float4*)&hh[8]  = hp[2];
        *(float4*)&hh[12] = hp[3];
#pragma unroll
        for (int k = 0; k < KNN; ++k)
            y[k] = fmaf(hh[k], w2dc, y[k]);
    }

    float acc = 0.f;
#pragma unroll
    for (int k = 0; k < KNN; ++k) {
        float gfv = f[((size_t)b * N + nidx[k]) * 64 + c];  // coalesced row
        acc = fmaf(y[k] + b2c, gfv, acc);
    }
    out[(size_t)gq * 64 + c] = acc * 0.25f;   // 1/sqrt(16)
}

extern "C" void kernel_launch(void* const* d_in, const int* in_sizes, int n_in,
                              void* d_out, int out_size, void* d_ws, size_t ws_size,
                              hipStream_t stream) {
    const float* feature1 = (const float*)d_in[0];
    const float* xyz1     = (const float*)d_in[1];
    const float* xyz2     = (const float*)d_in[2];
    const float* Wp       = (const float*)d_in[3];
    const float* bp       = (const float*)d_in[4];
    const float* W1       = (const float*)d_in[5];
    const float* b1       = (const float*)d_in[6];
    const float* W2       = (const float*)d_in[7];
    const float* b2       = (const float*)d_in[8];
    float* out = (float*)d_out;

    char* w = (char*)d_ws;
    float4*   spts   = (float4*)w;    w += (size_t)B * N * 16;
    float4*   squery = (float4*)w;    w += (size_t)B * M * 16;
    float*    f      = (float*)w;     w += (size_t)B * N * D * 4;
    int*      sidx   = (int*)w;       w += (size_t)B * N * 4;
    unsigned* pcount = (unsigned*)w;  w += (size_t)B * NC * 4;
    unsigned* qcount = (unsigned*)w;  w += (size_t)B * NSC * 4;
    int*      misscnt= (int*)w;       w += 16;
    unsigned* pstart = (unsigned*)w;  w += (size_t)B * NC * 4;
    unsigned* pcur   = (unsigned*)w;  w += (size_t)B * NC * 4;
    unsigned* qcur   = (unsigned*)w;  w += (size_t)B * NSC * 4;
    int*      wtab   = (int*)w;       w += (size_t)B * WTMAX * 4;
    int*      ntab   = (int*)w;       w += 16;
    float*    partd  = (float*)w;     w += (size_t)NSL * KNN * BM * 4;
    int*      parti  = (int*)w;       w += (size_t)NSL * KNN * BM * 4;
    int*      misslist=(int*)w;       w += (size_t)BM * 4;
    int*      idxf   = (int*)w;       w += (size_t)KNN * BM * 4;
    float*    w_out  = out + (size_t)BM * D;

    // zero pcount + qcount + misscnt (contiguous)
    hipMemsetAsync(pcount, 0, (size_t)(B * NC + B * NSC) * 4 + 16, stream);

    k_count<<<BM / 256, 256, 0, stream>>>(xyz1, xyz2, pcount, qcount);
    k_scan<<<4, 256, 0, stream>>>(pcount, qcount, pstart, pcur, qcur, wtab, ntab);
    k_scatter<<<BM / 256, 256, 0, stream>>>(xyz1, xyz2, pcur, qcur, spts, sidx, squery);
    k_proj<<<B * N / 4, 256, 0, stream>>>(feature1, Wp, bp, f);
    k_knn<<<B * WTMAX * 2, 256, 0, stream>>>(spts, squery, pstart, pcount,
                                             wtab, ntab, partd, parti);
    k_merge<<<BM / 64, 256, 0, stream>>>(squery, partd, parti, sidx,
                                         idxf, w_out, misscnt, misslist);
    k_fix<<<64, 64, 0, stream>>>(spts, sidx, squery, misscnt, misslist, idxf, w_out);
    k_final<<<BM / 4, 256, 0, stream>>>(xyz1, xyz2, f, idxf, W1, b1, W2, b2, out);
}

// Round 8
// 286.439 us; speedup vs baseline: 1.7558x; 1.0235x over previous
//
#include <hip/hip_runtime.h>
#include <math.h>

#define B 2
#define N 8192
#define M 8192
#define D 64
#define KNN 16
#define BM (B * M)           // 16384
#define GC 16                // grid cells per axis
#define NC (GC * GC * GC)    // 4096
#define NSC 64               // supercells (4x4x4)
#define WTMAX 192            // max wave-table entries per batch (proven bound)
#define NSL 8                // candidate slices (waves) per query group
#define CAP 20               // per-lane LDS candidate buffer slots
#define TCAP 448             // per-wave LDS point-tile capacity

// Per-query filter radius: lambda~60 expected in-(clipped-)ball candidates.
// nc = #axes within 0.16 of a domain wall (density octant compensation).
// MUST be recomputed identically in k_knn and k_merge.
__device__ __forceinline__ float query_cutr(float qx, float qy, float qz) {
    int nc = ((qx < 0.16f) | (qx > 0.84f)) + ((qy < 0.16f) | (qy > 0.84f))
           + ((qz < 0.16f) | (qz > 0.84f));
    return nc == 0 ? 0.121f : nc == 1 ? 0.1525f : nc == 2 ? 0.1921f : 0.242f;
}

// Sorted-insert of (dd,ii) into per-lane top-16 (v ascending). Strict < keeps
// earlier-inserted on exact ties.
#define CHAIN_INSERT(DVAL, IVAL) do {                                   \
    float _dd = (DVAL); int _ii = (IVAL);                               \
    _Pragma("unroll")                                                   \
    for (int _r = 0; _r < KNN; ++_r) {                                  \
        bool  _sm = _dd < v[_r];                                        \
        float _tv = v[_r]; int _ti = id[_r];                            \
        v[_r]  = _sm ? _dd : _tv;  id[_r] = _sm ? _ii : _ti;            \
        _dd    = _sm ? _tv : _dd;  _ii    = _sm ? _ti : _ii;            \
    }                                                                   \
} while (0)

// Scan the wave's tile (broadcast ds_read_b128), buffer passers, drain, reset.
#define KFLUSH() do {                                                   \
    for (int _t = 0; _t < cur; ++_t) {                                  \
        float4 _p = tile[wv][_t];              /* bcast, conflict-free */\
        float _dv = fmaf(ax, _p.x, _p.w);                               \
        _dv = fmaf(ay, _p.y, _dv);                                      \
        _dv = fmaf(az, _p.z, _dv);                                      \
        if (_dv < fcut) {                                               \
            if (cnt < CAP) {                                            \
                ibuf[cnt][tid] = (unsigned short)_t;                    \
                ++cnt;                                                  \
            } else {                           /* overflow (rare) */    \
                CHAIN_INSERT(_dv, (int)tgid[wv][_t]);                   \
            }                                                           \
        }                                                               \
    }                                                                   \
    int _mx = cnt;                                                      \
    _Pragma("unroll")                                                   \
    for (int _o = 32; _o; _o >>= 1)                                     \
        _mx = max(_mx, __shfl_xor(_mx, _o, 64));                        \
    _mx = __builtin_amdgcn_readfirstlane(_mx);                          \
    for (int _t2 = 0; _t2 < _mx; ++_t2) {                               \
        int _tp = (_t2 < cnt) ? (int)ibuf[_t2][tid] : 0;                \
        float4 _p = tile[wv][_tp];             /* per-lane LDS gather */\
        float _dv = fmaf(ax, _p.x, _p.w);                               \
        _dv = fmaf(ay, _p.y, _dv);                                      \
        _dv = fmaf(az, _p.z, _dv);                                      \
        if (_t2 < cnt && _dv < v[KNN - 1])                              \
            CHAIN_INSERT(_dv, (int)tgid[wv][_tp]);                      \
    }                                                                   \
    cnt = 0; cur = 0;                                                   \
} while (0)

// ---------------------------------------------------------------------------
// Kernel: histogram points into 4096 linear cells, queries into 64 supercells.
__global__ __launch_bounds__(256) void k_count(const float* __restrict__ xyz1,
                                               const float* __restrict__ xyz2,
                                               unsigned* __restrict__ pcount,
                                               unsigned* __restrict__ qcount) {
    int i = blockIdx.x * 256 + threadIdx.x;   // < B*N
    int b = i >> 13;
    const float* p = xyz1 + (size_t)i * 3;
    int cx = max(0, min(GC - 1, (int)(p[0] * GC)));
    int cy = max(0, min(GC - 1, (int)(p[1] * GC)));
    int cz = max(0, min(GC - 1, (int)(p[2] * GC)));
    atomicAdd(&pcount[b * NC + (cz * GC + cy) * GC + cx], 1u);
    const float* q = xyz2 + (size_t)i * 3;
    int qx = max(0, min(GC - 1, (int)(q[0] * GC)));
    int qy = max(0, min(GC - 1, (int)(q[1] * GC)));
    int qz = max(0, min(GC - 1, (int)(q[2] * GC)));
    int sc = ((qz >> 2) * 4 + (qy >> 2)) * 4 + (qx >> 2);
    atomicAdd(&qcount[b * NSC + sc], 1u);
}

// Kernel: blocks 0,1 = 4096-bin exclusive scan (points, per batch);
//         blocks 2,3 = 64-bin query scan + wave-table build (serial, tiny).
// wtab entry packs (qoff<<7) | qnum.
__global__ __launch_bounds__(256) void k_scan(const unsigned* __restrict__ pcount,
                                              const unsigned* __restrict__ qcount,
                                              unsigned* __restrict__ pstart,
                                              unsigned* __restrict__ pcur,
                                              unsigned* __restrict__ qcur,
                                              int* __restrict__ wtab,
                                              int* __restrict__ ntab) {
    __shared__ unsigned wsum[4];
    int blk = blockIdx.x;
    if (blk < 2) {
        int b = blk;
        int t = threadIdx.x;
        int base = b * NC + t * 16;
        unsigned c[16]; unsigned tsum = 0;
#pragma unroll
        for (int k = 0; k < 16; ++k) { c[k] = pcount[base + k]; tsum += c[k]; }
        int lane = t & 63, wv = t >> 6;
        unsigned x = tsum;
#pragma unroll
        for (int off = 1; off < 64; off <<= 1) {
            unsigned y = __shfl_up(x, off, 64);
            if (lane >= off) x += y;
        }
        if (lane == 63) wsum[wv] = x;
        __syncthreads();
        unsigned pre = 0;
        for (int k2 = 0; k2 < wv; ++k2) pre += wsum[k2];
        unsigned run = pre + x - tsum;
#pragma unroll
        for (int k = 0; k < 16; ++k) {
            pstart[base + k] = run; pcur[base + k] = run; run += c[k];
        }
    } else {
        int b = blk - 2;
        if (threadIdx.x != 0) return;
        int run = 0, nw = 0;
        for (int sc = 0; sc < NSC; ++sc) {
            int c = (int)qcount[b * NSC + sc];
            qcur[b * NSC + sc] = (unsigned)run;
            for (int o = 0; o < c; o += 64) {
                int num = min(64, c - o);
                wtab[b * WTMAX + nw++] = ((run + o) << 7) | num;
            }
            run += c;
        }
        ntab[b] = nw;
    }
}

// Kernel: scatter points (cell-sorted, with |p|^2) and queries (supercell-sorted).
__global__ __launch_bounds__(256) void k_scatter(const float* __restrict__ xyz1,
                                                 const float* __restrict__ xyz2,
                                                 unsigned* __restrict__ pcur,
                                                 unsigned* __restrict__ qcur,
                                                 float4* __restrict__ spts,
                                                 int* __restrict__ sidx,
                                                 float4* __restrict__ squery) {
    int i = blockIdx.x * 256 + threadIdx.x;   // < B*N
    int b = i >> 13;
    const float* p = xyz1 + (size_t)i * 3;
    float x = p[0], y = p[1], z = p[2];
    int cx = max(0, min(GC - 1, (int)(x * GC)));
    int cy = max(0, min(GC - 1, (int)(y * GC)));
    int cz = max(0, min(GC - 1, (int)(z * GC)));
    unsigned pos = atomicAdd(&pcur[b * NC + (cz * GC + cy) * GC + cx], 1u);
    spts[(size_t)b * N + pos] = make_float4(x, y, z, fmaf(x, x, fmaf(y, y, z * z)));
    sidx[(size_t)b * N + pos] = i & (N - 1);

    const float* q = xyz2 + (size_t)i * 3;
    float qx = q[0], qy = q[1], qz = q[2];
    int ax = max(0, min(GC - 1, (int)(qx * GC)));
    int ay = max(0, min(GC - 1, (int)(qy * GC)));
    int az = max(0, min(GC - 1, (int)(qz * GC)));
    int sc = ((az >> 2) * 4 + (ay >> 2)) * 4 + (ax >> 2);
    unsigned qpos = atomicAdd(&qcur[b * NSC + sc], 1u);
    squery[(size_t)b * M + qpos] = make_float4(qx, qy, qz, __int_as_float(i));
}

// Kernel: f = feature1 @ Wp + bp. Wave per 8 rows, lane = output channel.
// Wp column c lives in 64 VGPRs; row values broadcast via shfl; 8 independent
// fp32 acc chains (same d-order as before => bit-identical f).
__global__ __launch_bounds__(256) void k_proj(const float* __restrict__ feat,
                                              const float* __restrict__ Wp,
                                              const float* __restrict__ bp,
                                              float* __restrict__ f) {
    int c  = threadIdx.x & 63;
    int wv = threadIdx.x >> 6;
    int row0 = blockIdx.x * 32 + wv * 8;
    float wp[64];
#pragma unroll
    for (int d = 0; d < 64; ++d) wp[d] = Wp[d * 64 + c];   // coalesced, L1-hot
    float bpc = bp[c];
    float fv[8], acc[8];
#pragma unroll
    for (int r = 0; r < 8; ++r) {
        fv[r]  = feat[(size_t)(row0 + r) * 64 + c];        // coalesced
        acc[r] = bpc;
    }
#pragma unroll
    for (int d = 0; d < 64; ++d) {
#pragma unroll
        for (int r = 0; r < 8; ++r)
            acc[r] = fmaf(__shfl(fv[r], d, 64), wp[d], acc[r]);
    }
#pragma unroll
    for (int r = 0; r < 8; ++r)
        f[(size_t)(row0 + r) * 64 + c] = acc[r];
}

// Kernel: grid KNN partials, slice-parallel. Block = 4 waves; each wave = one
// of 8 candidate slices of a 64-query group (2 blocks per group).
// Box = wave-reduced bbox of [q - cutr, q + cutr] over the group's queries.
// Wave stages its rows (rix % 8 == s) into a per-wave LDS tile with
// cooperative vector loads, then scans via broadcast ds_read_b128; passers
// buffered (conflict-free u16), drained at tile flush; sorted 16-partial out.
__global__ __launch_bounds__(256) void k_knn(const float4* __restrict__ spts,
                                             const float4* __restrict__ squery,
                                             const unsigned* __restrict__ pstart,
                                             const unsigned* __restrict__ pcount,
                                             const int* __restrict__ wtab,
                                             const int* __restrict__ ntab,
                                             float* __restrict__ part_d,
                                             int* __restrict__ part_i) {
    __shared__ float4         tile[4][TCAP];    // 28 KB, per-wave
    __shared__ unsigned short tgid[4][TCAP];    // 3.5 KB (tile -> sorted idx)
    __shared__ unsigned short ibuf[CAP][256];   // 10 KB, [slot][tid]
    int bid = blockIdx.x;
    int b   = bid / (WTMAX * 2);
    int rem = bid - b * (WTMAX * 2);
    int ti  = rem >> 1;
    int sq  = rem & 1;
    if (ti >= ntab[b]) return;
    int e = wtab[b * WTMAX + ti];
    int qnum = e & 127, qoff = (e >> 7) & 0x3FFF;
    int tid = threadIdx.x;
    int lane = tid & 63;
    int wv = tid >> 6;
    int s = sq * 4 + wv;                        // slice 0..7

    int sl = lane < qnum ? lane : qnum - 1;     // surplus lanes dup last query
    float4 q4 = squery[(size_t)b * M + qoff + sl];
    float qx = q4.x, qy = q4.y, qz = q4.z;
    float ax = -2.f * qx, ay = -2.f * qy, az = -2.f * qz;
    float q2 = fmaf(qx, qx, fmaf(qy, qy, qz * qz));
    float cutr = query_cutr(qx, qy, qz);
    float fcut = cutr * cutr - q2;              // filter in dv = d^2 - q^2 space

    // per-lane cell box of the filter ball, then wave-reduced group box
    int lx0 = max(0, (int)floorf((qx - cutr) * GC));
    int lx1 = min(GC - 1, (int)floorf((qx + cutr) * GC));
    int ly0 = max(0, (int)floorf((qy - cutr) * GC));
    int ly1 = min(GC - 1, (int)floorf((qy + cutr) * GC));
    int lz0 = max(0, (int)floorf((qz - cutr) * GC));
    int lz1 = min(GC - 1, (int)floorf((qz + cutr) * GC));
#pragma unroll
    for (int off = 1; off < 64; off <<= 1) {
        lx0 = min(lx0, __shfl_xor(lx0, off, 64));
        lx1 = max(lx1, __shfl_xor(lx1, off, 64));
        ly0 = min(ly0, __shfl_xor(ly0, off, 64));
        ly1 = max(ly1, __shfl_xor(ly1, off, 64));
        lz0 = min(lz0, __shfl_xor(lz0, off, 64));
        lz1 = max(lz1, __shfl_xor(lz1, off, 64));
    }
    int bx0 = __builtin_amdgcn_readfirstlane(lx0);
    int bx1 = __builtin_amdgcn_readfirstlane(lx1);
    int by0 = __builtin_amdgcn_readfirstlane(ly0);
    int by1 = __builtin_amdgcn_readfirstlane(ly1);
    int bz0 = __builtin_amdgcn_readfirstlane(lz0);
    int bz1 = __builtin_amdgcn_readfirstlane(lz1);

    float v[KNN]; int id[KNN];
#pragma unroll
    for (int r = 0; r < KNN; ++r) { v[r] = 3.4e38f; id[r] = 0; }
    int cnt = 0, cur = 0;
    int pb = b * N, cb = b * NC;
    int xspan = bx1 - bx0;

    int rix = 0;
    for (int zz = bz0; zz <= bz1; ++zz)
        for (int yy = by0; yy <= by1; ++yy, ++rix) {
            if ((rix & 7) != s) continue;       // this wave's rows only
            int codeL = cb + (zz * GC + yy) * GC + bx0;   // uniform
            int st = (int)pstart[codeL];
            int en = (int)pstart[codeL + xspan] + (int)pcount[codeL + xspan];
            st = __builtin_amdgcn_readfirstlane(st);
            en = __builtin_amdgcn_readfirstlane(en);
            int len = en - st;
            if (cur + len > TCAP) KFLUSH();
            for (int u = lane; u < len; u += 64) {        // vector loads
                tile[wv][cur + u] = spts[pb + st + u];
                tgid[wv][cur + u] = (unsigned short)(st + u);
            }
            cur += len;
        }
    KFLUSH();

    if (lane < qnum) {
        int col = b * M + qoff + lane;          // sorted-query column
#pragma unroll
        for (int r = 0; r < KNN; ++r) {
            part_d[(size_t)(s * KNN + r) * BM + col] = v[r];
            part_i[(size_t)(s * KNN + r) * BM + col] = id[r];
        }
    }
}

// Kernel: merge 8x16 partials per sorted query (2-stage, coalesced), emit
// final idx + weight; verify exactness bound (d16 < cutr), else miss-list.
__global__ __launch_bounds__(256) void k_merge(const float4* __restrict__ squery,
                                               const float* __restrict__ part_d,
                                               const int* __restrict__ part_i,
                                               const int* __restrict__ sidx,
                                               int* __restrict__ idx_out,
                                               float* __restrict__ w_out,
                                               int* __restrict__ misscnt,
                                               int* __restrict__ misslist) {
    __shared__ float sd[4][KNN][64];    // 16 KB
    __shared__ int   si[4][KNN][64];    // 16 KB
    int ql  = threadIdx.x & 63;
    int sub = threadIdx.x >> 6;
    int sqid = blockIdx.x * 64 + ql;    // 0..BM-1
    int b = sqid >> 13;

    float v[KNN]; int id[KNN];
#pragma unroll
    for (int r = 0; r < KNN; ++r) { v[r] = 3.4e38f; id[r] = 0; }

#pragma unroll 4
    for (int e = sub * 32; e < sub * 32 + 32; ++e) {
        float dv = part_d[(size_t)e * BM + sqid];      // coalesced
        if (dv < v[KNN - 1]) {
            int ii = part_i[(size_t)e * BM + sqid];
            CHAIN_INSERT(dv, ii);
        }
    }
#pragma unroll
    for (int r = 0; r < KNN; ++r) { sd[sub][r][ql] = v[r]; si[sub][r][ql] = id[r]; }
    __syncthreads();
    if (sub != 0) return;

    for (int e = KNN; e < 4 * KNN; ++e) {
        float dv = sd[e >> 4][e & 15][ql];
        if (dv < v[KNN - 1]) CHAIN_INSERT(dv, si[e >> 4][e & 15][ql]);
    }

    float4 q4 = squery[sqid];
    float qx = q4.x, qy = q4.y, qz = q4.z;
    int gq = __float_as_int(q4.w);
    float q2 = fmaf(qx, qx, fmaf(qy, qy, qz * qz));
    float cutr = query_cutr(qx, qy, qz);

    w_out[gq] = (v[0] + q2 > 0.03f) ? 10.0f : 1.0f;
#pragma unroll
    for (int r = 0; r < KNN; ++r)
        idx_out[(size_t)r * BM + gq] = sidx[b * N + id[r]];

    if (!(v[KNN - 1] + q2 < cutr * cutr * 0.9999f)) {  // exactness check
        int slot = atomicAdd(misscnt, 1);
        misslist[slot] = sqid;
    }
}

// Kernel: brute-force fixup for missed queries (normally zero work).
// One wave per query (grid-stride): per-lane top-16 over N/64 points, then a
// cross-lane bitonic tournament merge (6 rounds) -> global top-16 on all lanes.
__global__ __launch_bounds__(64) void k_fix(const float4* __restrict__ spts,
                                            const int* __restrict__ sidx,
                                            const float4* __restrict__ squery,
                                            const int* __restrict__ misscnt,
                                            const int* __restrict__ misslist,
                                            int* __restrict__ idx_out,
                                            float* __restrict__ w_out) {
    int lane = threadIdx.x;
    int nmiss = misscnt[0];
    for (int qi = blockIdx.x; qi < nmiss; qi += 64) {
        int sqid = misslist[qi];
        int b = sqid >> 13;
        float4 q4 = squery[sqid];
        float qx = q4.x, qy = q4.y, qz = q4.z;
        float ax = -2.f * qx, ay = -2.f * qy, az = -2.f * qz;
        float q2 = fmaf(qx, qx, fmaf(qy, qy, qz * qz));

        float v[KNN]; int id[KNN];
#pragma unroll
        for (int r = 0; r < KNN; ++r) { v[r] = 3.4e38f; id[r] = 0; }
        for (int t = lane; t < N; t += 64) {
            float4 p = spts[(size_t)b * N + t];
            float dv = fmaf(ax, p.x, p.w);
            dv = fmaf(ay, p.y, dv);
            dv = fmaf(az, p.z, dv);
            if (dv < v[KNN - 1]) CHAIN_INSERT(dv, t);
        }
        // bitonic tournament: after 6 rounds every lane holds global top-16
#pragma unroll
        for (int rd = 0; rd < 6; ++rd) {
            int dl = 1 << rd;
            float nv[KNN]; int nid[KNN];
#pragma unroll
            for (int i = 0; i < KNN; ++i) {          // half-cleaner vs partner
                float pv = __shfl_xor(v[KNN - 1 - i], dl, 64);
                int   pi = __shfl_xor(id[KNN - 1 - i], dl, 64);
                bool take = v[i] <= pv;
                nv[i]  = take ? v[i] : pv;
                nid[i] = take ? id[i] : pi;
            }
#pragma unroll
            for (int st = 8; st; st >>= 1) {         // sort bitonic 16-seq
#pragma unroll
                for (int i = 0; i < KNN; ++i) {
                    if (!(i & st)) {
                        int j = i | st;
                        bool sw = nv[i] > nv[j];
                        float ta = sw ? nv[j] : nv[i];
                        float tb = sw ? nv[i] : nv[j];
                        int ia = sw ? nid[j] : nid[i];
                        int ib = sw ? nid[i] : nid[j];
                        nv[i] = ta; nv[j] = tb; nid[i] = ia; nid[j] = ib;
                    }
                }
            }
#pragma unroll
            for (int i = 0; i < KNN; ++i) { v[i] = nv[i]; id[i] = nid[i]; }
        }
        if (lane == 0) {
            int gq = __float_as_int(q4.w);
            w_out[gq] = (v[0] + q2 > 0.03f) ? 10.0f : 1.0f;
#pragma unroll
            for (int r = 0; r < KNN; ++r)
                idx_out[(size_t)r * BM + gq] = sidx[b * N + id[r]];
        }
    }
}

// Kernel: gather + MLP + reduce. One wave per query, lane = channel c.
__global__ __launch_bounds__(256) void k_final(const float* __restrict__ xyz1,
                                               const float* __restrict__ xyz2,
                                               const float* __restrict__ f,
                                               const int* __restrict__ idx,
                                               const float* __restrict__ W1,
                                               const float* __restrict__ b1,
                                               const float* __restrict__ W2,
                                               const float* __restrict__ b2,
                                               float* __restrict__ out) {
    __shared__ float w2s[64 * 64];      // 16 KB, [d][c]
    __shared__ float hT[4][64 * 16];    // 16 KB, per-wave [d][k]

    for (int t = threadIdx.x; t < 64 * 16; t += 256)
        ((float4*)w2s)[t] = ((const float4*)W2)[t];

    int wv = threadIdx.x >> 6;
    int c  = threadIdx.x & 63;
    int gq = blockIdx.x * 4 + wv;
    int b  = gq >> 13;

    const float* q = xyz2 + (size_t)gq * 3;
    float qx = q[0], qy = q[1], qz = q[2];
    float w10 = W1[c], w11 = W1[64 + c], w12 = W1[128 + c];
    float b1c = b1[c], b2c = b2[c];

    int nidx[KNN];
#pragma unroll
    for (int k = 0; k < KNN; ++k)
        nidx[k] = idx[(size_t)k * BM + gq];      // wave-broadcast load

    float h[KNN];
#pragma unroll
    for (int k = 0; k < KNN; ++k) {
        const float* p = xyz1 + ((size_t)b * N + nidx[k]) * 3;
        float gx = p[0] - qx, gy = p[1] - qy, gz = p[2] - qz;
        float t = fmaf(gx, w10, b1c);
        t = fmaf(gy, w11, t);
        t = fmaf(gz, w12, t);
        h[k] = fmaxf(t, 0.f);
    }

#pragma unroll
    for (int k = 0; k < KNN; k += 4)
        *(float4*)&hT[wv][c * 16 + k] = make_float4(h[k], h[k+1], h[k+2], h[k+3]);

    __syncthreads();   // covers W2 staging + hT visibility

    float y[KNN];
#pragma unroll
    for (int k = 0; k < KNN; ++k) y[k] = 0.f;

#pragma unroll 4
    for (int d = 0; d < 64; ++d) {
        float w2dc = w2s[d * 64 + c];                       // conflict-free
        const float4* hp = (const float4*)&hT[wv][d * 16];  // broadcast reads
        float hh[16];
        *(float4*)&hh[0]  = hp[0];
        *(float4*)&hh[4]  = hp[1];
        *(float4*)&hh[8]  = hp[2];
        *(float4*)&hh[12] = hp[3];
#pragma unroll
        for (int k = 0; k < KNN; ++k)
            y[k] = fmaf(hh[k], w2dc, y[k]);
    }

    float acc = 0.f;
#pragma unroll
    for (int k = 0; k < KNN; ++k) {
        float gfv = f[((size_t)b * N + nidx[k]) * 64 + c];  // coalesced row
        acc = fmaf(y[k] + b2c, gfv, acc);
    }
    out[(size_t)gq * 64 + c] = acc * 0.25f;   // 1/sqrt(16)
}

extern "C" void kernel_launch(void* const* d_in, const int* in_sizes, int n_in,
                              void* d_out, int out_size, void* d_ws, size_t ws_size,
                              hipStream_t stream) {
    const float* feature1 = (const float*)d_in[0];
    const float* xyz1     = (const float*)d_in[1];
    const float* xyz2     = (const float*)d_in[2];
    const float* Wp       = (const float*)d_in[3];
    const float* bp       = (const float*)d_in[4];
    const float* W1       = (const float*)d_in[5];
    const float* b1       = (const float*)d_in[6];
    const float* W2       = (const float*)d_in[7];
    const float* b2       = (const float*)d_in[8];
    float* out = (float*)d_out;

    char* w = (char*)d_ws;
    float4*   spts   = (float4*)w;    w += (size_t)B * N * 16;
    float4*   squery = (float4*)w;    w += (size_t)B * M * 16;
    float*    f      = (float*)w;     w += (size_t)B * N * D * 4;
    int*      sidx   = (int*)w;       w += (size_t)B * N * 4;
    unsigned* pcount = (unsigned*)w;  w += (size_t)B * NC * 4;
    unsigned* qcount = (unsigned*)w;  w += (size_t)B * NSC * 4;
    int*      misscnt= (int*)w;       w += 16;
    unsigned* pstart = (unsigned*)w;  w += (size_t)B * NC * 4;
    unsigned* pcur   = (unsigned*)w;  w += (size_t)B * NC * 4;
    unsigned* qcur   = (unsigned*)w;  w += (size_t)B * NSC * 4;
    int*      wtab   = (int*)w;       w += (size_t)B * WTMAX * 4;
    int*      ntab   = (int*)w;       w += 16;
    float*    partd  = (float*)w;     w += (size_t)NSL * KNN * BM * 4;
    int*      parti  = (int*)w;       w += (size_t)NSL * KNN * BM * 4;
    int*      misslist=(int*)w;       w += (size_t)BM * 4;
    int*      idxf   = (int*)w;       w += (size_t)KNN * BM * 4;
    float*    w_out  = out + (size_t)BM * D;

    // zero pcount + qcount + misscnt (contiguous)
    hipMemsetAsync(pcount, 0, (size_t)(B * NC + B * NSC) * 4 + 16, stream);

    k_count<<<BM / 256, 256, 0, stream>>>(xyz1, xyz2, pcount, qcount);
    k_scan<<<4, 256, 0, stream>>>(pcount, qcount, pstart, pcur, qcur, wtab, ntab);
    k_scatter<<<BM / 256, 256, 0, stream>>>(xyz1, xyz2, pcur, qcur, spts, sidx, squery);
    k_proj<<<B * N / 32, 256, 0, stream>>>(feature1, Wp, bp, f);
    k_knn<<<B * WTMAX * 2, 256, 0, stream>>>(spts, squery, pstart, pcount,
                                             wtab, ntab, partd, parti);
    k_merge<<<BM / 64, 256, 0, stream>>>(squery, partd, parti, sidx,
                                         idxf, w_out, misscnt, misslist);
    k_fix<<<64, 64, 0, stream>>>(spts, sidx, squery, misscnt, misslist, idxf, w_out);
    k_final<<<BM / 4, 256, 0, stream>>>(xyz1, xyz2, f, idxf, W1, b1, W2, b2, out);
}